// Round 8
// baseline (100.772 us; speedup 1.0000x reference)
//
#include <hip/hip_runtime.h>

// KAN B-spline layer via MFMA — (Mt,Nt)=(2,2), B-in-registers, ZERO LDS,
// ZERO barriers. out[b,o] = sum_k basis[b,k] * W[k,o], k = 12*feat + c (K=768).
// k-map (same bijection on A and B -> HW-wiring invariant, proven r2-r7):
//   k = 192*g + 8*s + e   (g = lane>>4, s = 0..23, e = 0..7)
// Wave tile: 32 rows x 32 cols. 4096 waves total -> 4 waves/SIMD resident.
// Per k-eighth (3 steps = 2 features per g): load 6 B-frags from packed wfrag
// (L2), eval 4 basis rows in regs, 12 MFMAs. No __syncthreads anywhere ->
// compiler freely pipelines next-phase loads under eval/MFMA.

typedef short short8 __attribute__((ext_vector_type(8)));
typedef float f32x4 __attribute__((ext_vector_type(4)));
typedef unsigned u32x4 __attribute__((ext_vector_type(4)));

#define THREADS 256       // 4 waves/block; block = 64 rows x 64 cols

static __device__ __forceinline__ unsigned bf16rne(float f) {
  unsigned u = __float_as_uint(f);
  return (u + 0x7FFFu + ((u >> 16) & 1u)) >> 16;   // RNE, low 16 bits valid
}

// ---- prep: pack W bf16 B-frags, layout [nt(4)][s(24)][lane(64)][4 dw] ----
__global__ __launch_bounds__(256) void prep_wfrag(const float* __restrict__ cp,
                                                  unsigned* __restrict__ wfrag) {
  int id = blockIdx.x * 256 + threadIdx.x;   // 0..24575 dwords
  int d  = id & 3;
  int l  = (id >> 2) & 63;
  int id2 = id >> 8;               // 0..95 = nt*24 + s
  int nt = id2 / 24;
  int s  = id2 - nt * 24;
  int g  = l >> 4;
  int o  = nt * 16 + (l & 15);
  int k0 = 192 * g + 8 * s + 2 * d;
  unsigned lo = bf16rne(cp[k0 * 64 + o]);
  unsigned hi = bf16rne(cp[(k0 + 1) * 64 + o]);
  wfrag[id] = lo | (hi << 16);
}

struct Pack6 { unsigned w0, w1, w2, w3, w4, w5; };   // dense-12 bf16

static __device__ __forceinline__ Pack6 eval_pack(float xi) {
  xi = fminf(fmaxf(xi, 0.0f), 1.0f);
  float t9 = xi * 9.0f;
  int jj = (int)t9;
  float validf = (jj <= 8) ? 1.0f : 0.0f;   // x==1 -> zero row (ref semantics)
  jj = (jj > 8) ? 8 : jj;
  float fj = (float)jj;
  float u  = t9 - fj;
  float omu = 1.0f - u;
  float c1  = fminf(fj, 1.0f);
  float c2  = fminf(fj, 2.0f);
  float rdj = 9.0f - fj;
  float d2p = fminf(rdj, 2.0f);
  float d3p = fminf(rdj, 3.0f);
  float invA = (jj == 0) ? 1.0f : 0.5f;
  float invB = (jj == 8) ? 1.0f : 0.5f;
  float invC = (jj == 0) ? 1.0f : ((jj == 1) ? 0.5f : (1.0f / 3.0f));
  float invD = (jj == 0 || jj == 8) ? 0.5f : (1.0f / 3.0f);
  float invE = (jj >= 7) ? ((jj == 8) ? 1.0f : 0.5f) : (1.0f / 3.0f);
  float xkm1 = u + c1, xkm2 = u + c2;
  float k2x = d2p - u, k3x = d3p - u;
  float t0 = omu * invA;
  float A0 = omu * t0;
  float s1 = xkm1 * t0;
  float t1 = u * invB;
  float A1 = fmaf(k2x, t1, s1);
  float A2 = u * t1;
  float u0 = A0 * invC;
  float B0 = omu * u0;
  float s2 = xkm2 * u0;
  float u1 = A1 * invD;
  float B1 = fmaf(k2x, u1, s2);
  float s3 = xkm1 * u1;
  float u2 = A2 * invE;
  float B2 = fmaf(k3x, u2, s3);
  float B3 = u * u2;
  B0 *= validf; B1 *= validf; B2 *= validf; B3 *= validf;

  unsigned b0 = bf16rne(B0), b1 = bf16rne(B1), b2 = bf16rne(B2), b3 = bf16rne(B3);
  unsigned p01 = b0 | (b1 << 16);
  unsigned p23 = b2 | (b3 << 16);
  unsigned O0 = p01 << 16;
  unsigned O1 = (p01 >> 16) | (p23 << 16);
  unsigned O2 = p23 >> 16;
  int e2 = jj >> 1;
  bool odd = (jj & 1) != 0;
#define VE(q) ((q == e2) ? p01 : ((q == e2 + 1) ? p23 : 0u))
#define VO(q) ((q == e2) ? O0 : ((q == e2 + 1) ? O1 : ((q == e2 + 2) ? O2 : 0u)))
  Pack6 r;
  r.w0 = odd ? VO(0) : VE(0);
  r.w1 = odd ? VO(1) : VE(1);
  r.w2 = odd ? VO(2) : VE(2);
  r.w3 = odd ? VO(3) : VE(3);
  r.w4 = odd ? VO(4) : VE(4);
  r.w5 = odd ? VO(5) : VE(5);
#undef VE
#undef VO
  return r;
}

__global__ __launch_bounds__(THREADS, 4) void kan_mfma(const float* __restrict__ x,
                                                       const unsigned* __restrict__ wfrag,
                                                       float* __restrict__ out) {
  const int tid  = threadIdx.x;
  const int lane = tid & 63;
  const int w    = tid >> 6;
  const int m = lane & 15, g = lane >> 4;
  const long row0 = (long)blockIdx.x * 64 + (w >> 1) * 32;
  const int  ntb  = (w & 1) * 2;     // global 16-col tile base: 0 or 2

  // ---- x upfront: lane's 2 rows x its 16 feature cols (r5-proven pattern) ----
  float xr0[16], xr1[16];
  {
    const float4* p0 = (const float4*)(x + (row0 + m) * 64 + g * 16);
    const float4* p1 = (const float4*)(x + (row0 + 16 + m) * 64 + g * 16);
    #pragma unroll
    for (int q = 0; q < 4; ++q) {
      float4 v = p0[q];
      xr0[4 * q] = v.x; xr0[4 * q + 1] = v.y; xr0[4 * q + 2] = v.z; xr0[4 * q + 3] = v.w;
    }
    #pragma unroll
    for (int q = 0; q < 4; ++q) {
      float4 v = p1[q];
      xr1[4 * q] = v.x; xr1[4 * q + 1] = v.y; xr1[4 * q + 2] = v.z; xr1[4 * q + 3] = v.w;
    }
  }

  f32x4 acc[2][2];
  #pragma unroll
  for (int mt = 0; mt < 2; ++mt)
    #pragma unroll
    for (int ntl = 0; ntl < 2; ++ntl)
      acc[mt][ntl] = f32x4{0.0f, 0.0f, 0.0f, 0.0f};

  const u32x4* wf4 = (const u32x4*)wfrag;

  #pragma unroll
  for (int q = 0; q < 8; ++q) {
    // ---- 6 B-frags for this k-eighth (coalesced b128, L2-resident) ----
    u32x4 bq0[3], bq1[3];
    #pragma unroll
    for (int sub = 0; sub < 3; ++sub) {
      bq0[sub] = wf4[((ntb + 0) * 24 + 3 * q + sub) * 64 + lane];
      bq1[sub] = wf4[((ntb + 1) * 24 + 3 * q + sub) * 64 + lane];
    }
    // ---- 4 independent basis evals (features 16g+2q, 16g+2q+1; both rows) ----
    Pack6 aA = eval_pack(xr0[2 * q]);
    Pack6 aB = eval_pack(xr0[2 * q + 1]);
    Pack6 bA = eval_pack(xr1[2 * q]);
    Pack6 bB = eval_pack(xr1[2 * q + 1]);
    #pragma unroll
    for (int sub = 0; sub < 3; ++sub) {
      u32x4 qa, qb;
      if (sub == 0) {
        qa[0] = aA.w0; qa[1] = aA.w1; qa[2] = aA.w2; qa[3] = aA.w3;
        qb[0] = bA.w0; qb[1] = bA.w1; qb[2] = bA.w2; qb[3] = bA.w3;
      } else if (sub == 1) {
        qa[0] = aA.w4; qa[1] = aA.w5; qa[2] = aB.w0; qa[3] = aB.w1;
        qb[0] = bA.w4; qb[1] = bA.w5; qb[2] = bB.w0; qb[3] = bB.w1;
      } else {
        qa[0] = aB.w2; qa[1] = aB.w3; qa[2] = aB.w4; qa[3] = aB.w5;
        qb[0] = bB.w2; qb[1] = bB.w3; qb[2] = bB.w4; qb[3] = bB.w5;
      }
      short8 A0 = __builtin_bit_cast(short8, qa);
      short8 A1 = __builtin_bit_cast(short8, qb);
      short8 Bf0 = __builtin_bit_cast(short8, bq0[sub]);
      short8 Bf1 = __builtin_bit_cast(short8, bq1[sub]);
      acc[0][0] = __builtin_amdgcn_mfma_f32_16x16x32_bf16(A0, Bf0, acc[0][0], 0, 0, 0);
      acc[1][0] = __builtin_amdgcn_mfma_f32_16x16x32_bf16(A1, Bf0, acc[1][0], 0, 0, 0);
      acc[0][1] = __builtin_amdgcn_mfma_f32_16x16x32_bf16(A0, Bf1, acc[0][1], 0, 0, 0);
      acc[1][1] = __builtin_amdgcn_mfma_f32_16x16x32_bf16(A1, Bf1, acc[1][1], 0, 0, 0);
    }
  }

  // ---- stores: 16 contiguous dwords per 16-lane group ----
  #pragma unroll
  for (int mt = 0; mt < 2; ++mt)
    #pragma unroll
    for (int ntl = 0; ntl < 2; ++ntl)
      #pragma unroll
      for (int j = 0; j < 4; ++j)
        out[(row0 + mt * 16 + g * 4 + j) * 64 + (ntb + ntl) * 16 + m] = acc[mt][ntl][j];
}

extern "C" void kernel_launch(void* const* d_in, const int* in_sizes, int n_in,
                              void* d_out, int out_size, void* d_ws, size_t ws_size,
                              hipStream_t stream) {
  const float* x  = (const float*)d_in[0];
  const float* cp = (const float*)d_in[1];
  float* out = (float*)d_out;
  unsigned* wfrag = (unsigned*)d_ws;       // 24576 dwords = 96 KB

  hipLaunchKernelGGL(prep_wfrag, dim3(96), dim3(256), 0, stream, cp, wfrag);
  const int rows = in_sizes[0] / 64;       // 65536
  hipLaunchKernelGGL(kan_mfma, dim3(rows / 64), dim3(THREADS), 0, stream,
                     x, wfrag, out);
}

// Round 9
// 84.777 us; speedup vs baseline: 1.1887x; 1.1887x over previous
//
#include <hip/hip_runtime.h>

// KAN B-spline layer via MFMA — (Mt,Nt)=(1,4), B-in-registers, ZERO LDS,
// ZERO barriers, funnel-shift dense-12 placement.
// out[b,o] = sum_k basis[b,k] * W[k,o], k = 12*feat + c (K=768).
// k-map (same bijection on A and B -> HW-wiring invariant, proven r2-r8):
//   k = 192*g + 8*s + e   (g = lane>>4, s = 0..23, e = 0..7)
// Wave tile: 16 rows x 64 cols -> each x element evaluated exactly once.
// Per k-eighth q (3 steps = 2 features per g): load 12 B-frags (coalesced,
// L2/L1-resident), eval 2 basis values in regs (chunked into 3 u64 halves
// by 64-bit shifts), 12 MFMAs. 4096 waves -> 4 waves/SIMD.

typedef short short8 __attribute__((ext_vector_type(8)));
typedef float f32x4 __attribute__((ext_vector_type(4)));
typedef unsigned u32x4 __attribute__((ext_vector_type(4)));
typedef unsigned long long u64;

#define THREADS 256       // 4 waves/block; block = 64 rows x 64 cols

static __device__ __forceinline__ unsigned bf16rne(float f) {
  unsigned u = __float_as_uint(f);
  return (u + 0x7FFFu + ((u >> 16) & 1u)) >> 16;   // RNE, low 16 bits valid
}

// ---- prep: pack W bf16 B-frags, layout [nt(4)][s(24)][lane(64)][4 dw] ----
__global__ __launch_bounds__(256) void prep_wfrag(const float* __restrict__ cp,
                                                  unsigned* __restrict__ wfrag) {
  int id = blockIdx.x * 256 + threadIdx.x;   // 0..24575 dwords
  int d  = id & 3;
  int l  = (id >> 2) & 63;
  int id2 = id >> 8;               // 0..95 = nt*24 + s
  int nt = id2 / 24;
  int s  = id2 - nt * 24;
  int g  = l >> 4;
  int o  = nt * 16 + (l & 15);
  int k0 = 192 * g + 8 * s + 2 * d;
  unsigned lo = bf16rne(cp[k0 * 64 + o]);
  unsigned hi = bf16rne(cp[(k0 + 1) * 64 + o]);
  wfrag[id] = lo | (hi << 16);
}

// ---- basis eval -> three 64-bit chunks of the dense-12 bf16 row ----
// chunk cq = bf16 slots 4q..4q+3 = bits [64q,64q+64) of the 192-bit vector;
// payload (B0..B3 at slot jj) = P placed at bit 16*jj via guarded 64b shifts.
static __device__ __forceinline__ void eval_chunks(float xi, u64& c0, u64& c1, u64& c2) {
  xi = fminf(fmaxf(xi, 0.0f), 1.0f);
  float t9 = xi * 9.0f;
  int jj = (int)t9;
  float validf = (jj <= 8) ? 1.0f : 0.0f;   // x==1 -> zero row (ref semantics)
  jj = (jj > 8) ? 8 : jj;
  float fj = (float)jj;
  float u  = t9 - fj;
  float omu = 1.0f - u;
  float k1c = fminf(fj, 1.0f);
  float k2c = fminf(fj, 2.0f);
  float rdj = 9.0f - fj;
  float d2p = fminf(rdj, 2.0f);
  float d3p = fminf(rdj, 3.0f);
  float invA = (jj == 0) ? 1.0f : 0.5f;
  float invB = (jj == 8) ? 1.0f : 0.5f;
  float invC = (jj == 0) ? 1.0f : ((jj == 1) ? 0.5f : (1.0f / 3.0f));
  float invD = (jj == 0 || jj == 8) ? 0.5f : (1.0f / 3.0f);
  float invE = (jj >= 7) ? ((jj == 8) ? 1.0f : 0.5f) : (1.0f / 3.0f);
  float xkm1 = u + k1c, xkm2 = u + k2c;
  float k2x = d2p - u, k3x = d3p - u;
  float t0 = omu * invA;
  float A0 = omu * t0;
  float s1 = xkm1 * t0;
  float t1 = u * invB;
  float A1 = fmaf(k2x, t1, s1);
  float A2 = u * t1;
  float u0 = A0 * invC;
  float B0 = omu * u0;
  float s2 = xkm2 * u0;
  float u1 = A1 * invD;
  float B1 = fmaf(k2x, u1, s2);
  float s3 = xkm1 * u1;
  float u2 = A2 * invE;
  float B2 = fmaf(k3x, u2, s3);
  float B3 = u * u2;
  B0 *= validf; B1 *= validf; B2 *= validf; B3 *= validf;

  unsigned lo = bf16rne(B0) | (bf16rne(B1) << 16);
  unsigned hi = bf16rne(B2) | (bf16rne(B3) << 16);
  u64 P = (u64)lo | ((u64)hi << 32);
  int s0 = jj << 4;                 // bit offset 16*jj in [0,128]
  c0 = (s0 < 64) ? (P << (s0 & 63)) : 0ull;
  c1 = (s0 < 64) ? ((s0 == 0) ? 0ull : (P >> ((64 - s0) & 63)))
                 : ((s0 < 128) ? (P << ((s0 - 64) & 63)) : 0ull);
  c2 = (s0 > 64) ? (P >> ((128 - s0) & 63)) : 0ull;
}

static __device__ __forceinline__ short8 mk_frag(u64 lo64, u64 hi64) {
  u32x4 q = { (unsigned)lo64, (unsigned)(lo64 >> 32),
              (unsigned)hi64, (unsigned)(hi64 >> 32) };
  return __builtin_bit_cast(short8, q);
}

__global__ __launch_bounds__(THREADS, 4) void kan_mfma(const float* __restrict__ x,
                                                       const unsigned* __restrict__ wfrag,
                                                       float* __restrict__ out) {
  const int tid  = threadIdx.x;
  const int lane = tid & 63;
  const int w    = tid >> 6;
  const int m = lane & 15, g = lane >> 4;
  const long row0 = (long)blockIdx.x * 64 + w * 16;

  // ---- x upfront: lane's row x its 16 feature cols (contiguous 64B) ----
  float xr[16];
  {
    const float4* p0 = (const float4*)(x + (row0 + m) * 64 + g * 16);
    #pragma unroll
    for (int q = 0; q < 4; ++q) {
      float4 v = p0[q];
      xr[4 * q] = v.x; xr[4 * q + 1] = v.y; xr[4 * q + 2] = v.z; xr[4 * q + 3] = v.w;
    }
  }

  f32x4 acc[4];
  #pragma unroll
  for (int nt = 0; nt < 4; ++nt) acc[nt] = f32x4{0.0f, 0.0f, 0.0f, 0.0f};

  const u32x4* wf4 = (const u32x4*)wfrag;

  #pragma unroll
  for (int q = 0; q < 8; ++q) {
    // ---- 12 B-frags for this k-eighth (coalesced b128, L1/L2-resident) ----
    u32x4 bq[4][3];
    #pragma unroll
    for (int nt = 0; nt < 4; ++nt)
      #pragma unroll
      for (int sub = 0; sub < 3; ++sub)
        bq[nt][sub] = wf4[(nt * 24 + 3 * q + sub) * 64 + lane];

    // ---- 2 basis evals (features 16g+2q, 16g+2q+1 of this lane's row) ----
    u64 a0, a1, a2, b0, b1, b2;
    eval_chunks(xr[2 * q],     a0, a1, a2);
    eval_chunks(xr[2 * q + 1], b0, b1, b2);

    short8 A[3] = { mk_frag(a0, a1), mk_frag(a2, b0), mk_frag(b1, b2) };

    #pragma unroll
    for (int sub = 0; sub < 3; ++sub)
      #pragma unroll
      for (int nt = 0; nt < 4; ++nt)
        acc[nt] = __builtin_amdgcn_mfma_f32_16x16x32_bf16(
            A[sub], __builtin_bit_cast(short8, bq[nt][sub]), acc[nt], 0, 0, 0);
  }

  // ---- stores: 16 contiguous dwords per 16-lane group ----
  #pragma unroll
  for (int nt = 0; nt < 4; ++nt)
    #pragma unroll
    for (int j = 0; j < 4; ++j)
      out[(row0 + g * 4 + j) * 64 + nt * 16 + m] = acc[nt][j];
}

extern "C" void kernel_launch(void* const* d_in, const int* in_sizes, int n_in,
                              void* d_out, int out_size, void* d_ws, size_t ws_size,
                              hipStream_t stream) {
  const float* x  = (const float*)d_in[0];
  const float* cp = (const float*)d_in[1];
  float* out = (float*)d_out;
  unsigned* wfrag = (unsigned*)d_ws;       // 24576 dwords = 96 KB

  hipLaunchKernelGGL(prep_wfrag, dim3(96), dim3(256), 0, stream, cp, wfrag);
  const int rows = in_sizes[0] / 64;       // 65536
  hipLaunchKernelGGL(kan_mfma, dim3(rows / 64), dim3(THREADS), 0, stream,
                     x, wfrag, out);
}

// Round 10
// 81.727 us; speedup vs baseline: 1.2330x; 1.0373x over previous
//
#include <hip/hip_runtime.h>

// KAN B-spline layer via MFMA — Mt=2, Nt=4, SPLIT-K(2), B-in-registers,
// zero staging LDS, one barrier (end reduction only).
// out[b,o] = sum_k basis[b,k] * W[k,o], k = 12*feat + c (K=768).
// k-map (same bijection on A and B -> HW-wiring invariant, proven r2-r9):
//   k = 192*g + 8*s + e   (g = lane>>4, s = 0..23, e = 0..7)
// Wave tile: 32 rows x 64 cols x K/2. kh = K-half: s in [12kh, 12kh+12),
// features 16g+8kh .. +8. Each x element evaluated exactly once.
// Block: 8 waves = 4 row-tiles x 2 K-halves; pairs reduced through LDS.
// 512 blocks x 8 waves = 4096 waves -> 4 waves/SIMD.

typedef short short8 __attribute__((ext_vector_type(8)));
typedef float f32x4 __attribute__((ext_vector_type(4)));
typedef unsigned u32x4 __attribute__((ext_vector_type(4)));
typedef unsigned long long u64;

#define THREADS 512

static __device__ __forceinline__ unsigned bf16rne(float f) {
  unsigned u = __float_as_uint(f);
  return (u + 0x7FFFu + ((u >> 16) & 1u)) >> 16;   // RNE, low 16 bits valid
}

// ---- prep: pack W bf16 B-frags, layout [nt(4)][s(24)][lane(64)][4 dw] ----
__global__ __launch_bounds__(256) void prep_wfrag(const float* __restrict__ cp,
                                                  unsigned* __restrict__ wfrag) {
  int id = blockIdx.x * 256 + threadIdx.x;   // 0..24575 dwords
  int d  = id & 3;
  int l  = (id >> 2) & 63;
  int id2 = id >> 8;               // 0..95 = nt*24 + s
  int nt = id2 / 24;
  int s  = id2 - nt * 24;
  int g  = l >> 4;
  int o  = nt * 16 + (l & 15);
  int k0 = 192 * g + 8 * s + 2 * d;
  unsigned lo = bf16rne(cp[k0 * 64 + o]);
  unsigned hi = bf16rne(cp[(k0 + 1) * 64 + o]);
  wfrag[id] = lo | (hi << 16);
}

// ---- basis eval -> three 64-bit chunks of the dense-12 bf16 row (r9-verified) ----
static __device__ __forceinline__ void eval_chunks(float xi, u64& c0, u64& c1, u64& c2) {
  xi = fminf(fmaxf(xi, 0.0f), 1.0f);
  float t9 = xi * 9.0f;
  int jj = (int)t9;
  float validf = (jj <= 8) ? 1.0f : 0.0f;   // x==1 -> zero row (ref semantics)
  jj = (jj > 8) ? 8 : jj;
  float fj = (float)jj;
  float u  = t9 - fj;
  float omu = 1.0f - u;
  float k1c = fminf(fj, 1.0f);
  float k2c = fminf(fj, 2.0f);
  float rdj = 9.0f - fj;
  float d2p = fminf(rdj, 2.0f);
  float d3p = fminf(rdj, 3.0f);
  float invA = (jj == 0) ? 1.0f : 0.5f;
  float invB = (jj == 8) ? 1.0f : 0.5f;
  float invC = (jj == 0) ? 1.0f : ((jj == 1) ? 0.5f : (1.0f / 3.0f));
  float invD = (jj == 0 || jj == 8) ? 0.5f : (1.0f / 3.0f);
  float invE = (jj >= 7) ? ((jj == 8) ? 1.0f : 0.5f) : (1.0f / 3.0f);
  float xkm1 = u + k1c, xkm2 = u + k2c;
  float k2x = d2p - u, k3x = d3p - u;
  float t0 = omu * invA;
  float A0 = omu * t0;
  float s1 = xkm1 * t0;
  float t1 = u * invB;
  float A1 = fmaf(k2x, t1, s1);
  float A2 = u * t1;
  float u0 = A0 * invC;
  float B0 = omu * u0;
  float s2 = xkm2 * u0;
  float u1 = A1 * invD;
  float B1 = fmaf(k2x, u1, s2);
  float s3 = xkm1 * u1;
  float u2 = A2 * invE;
  float B2 = fmaf(k3x, u2, s3);
  float B3 = u * u2;
  B0 *= validf; B1 *= validf; B2 *= validf; B3 *= validf;

  unsigned lo = bf16rne(B0) | (bf16rne(B1) << 16);
  unsigned hi = bf16rne(B2) | (bf16rne(B3) << 16);
  u64 P = (u64)lo | ((u64)hi << 32);
  int s0 = jj << 4;                 // bit offset 16*jj in [0,128]
  c0 = (s0 < 64) ? (P << (s0 & 63)) : 0ull;
  c1 = (s0 < 64) ? ((s0 == 0) ? 0ull : (P >> ((64 - s0) & 63)))
                 : ((s0 < 128) ? (P << ((s0 - 64) & 63)) : 0ull);
  c2 = (s0 > 64) ? (P >> ((128 - s0) & 63)) : 0ull;
}

static __device__ __forceinline__ short8 mk_frag(u64 lo64, u64 hi64) {
  u32x4 q = { (unsigned)lo64, (unsigned)(lo64 >> 32),
              (unsigned)hi64, (unsigned)(hi64 >> 32) };
  return __builtin_bit_cast(short8, q);
}

__global__ __launch_bounds__(THREADS, 4) void kan_mfma(const float* __restrict__ x,
                                                       const unsigned* __restrict__ wfrag,
                                                       float* __restrict__ out) {
  __shared__ float red[4 * 64 * 33];   // 33 KB; stride 33 -> (lane+idx)%32 banks
  const int tid  = threadIdx.x;
  const int lane = tid & 63;
  const int w    = tid >> 6;
  const int kh   = w >> 2;            // K-half: s in [12kh,12kh+12), feats +8kh
  const int rt   = w & 3;             // row-tile within block
  const int m = lane & 15, g = lane >> 4;
  const long row0 = (long)blockIdx.x * 128 + rt * 32;

  // ---- x: lane's 2 rows x its 8 feature cols (contiguous 32B each) ----
  float xr0[8], xr1[8];
  {
    const float4* p0 = (const float4*)(x + (row0 + m) * 64 + g * 16 + kh * 8);
    const float4* p1 = (const float4*)(x + (row0 + 16 + m) * 64 + g * 16 + kh * 8);
    #pragma unroll
    for (int q = 0; q < 2; ++q) {
      float4 v = p0[q];
      xr0[4 * q] = v.x; xr0[4 * q + 1] = v.y; xr0[4 * q + 2] = v.z; xr0[4 * q + 3] = v.w;
      float4 v1 = p1[q];
      xr1[4 * q] = v1.x; xr1[4 * q + 1] = v1.y; xr1[4 * q + 2] = v1.z; xr1[4 * q + 3] = v1.w;
    }
  }

  f32x4 acc[2][4];
  #pragma unroll
  for (int mt = 0; mt < 2; ++mt)
    #pragma unroll
    for (int nt = 0; nt < 4; ++nt)
      acc[mt][nt] = f32x4{0.0f, 0.0f, 0.0f, 0.0f};

  const u32x4* wf4 = (const u32x4*)wfrag;

  #pragma unroll
  for (int q = 0; q < 4; ++q) {
    const int sbase = kh * 12 + 3 * q;

    // ---- B-frags nt 0,1 (6 x coalesced b128, L1/L2-resident) ----
    u32x4 b01[2][3];
    #pragma unroll
    for (int nt = 0; nt < 2; ++nt)
      #pragma unroll
      for (int sub = 0; sub < 3; ++sub)
        b01[nt][sub] = wf4[(nt * 24 + sbase + sub) * 64 + lane];

    // ---- 4 evals: feats (16g+8kh+2q, +1) x rows (m, 16+m) ----
    u64 a0, a1, a2, b0, b1, b2;
    eval_chunks(xr0[2 * q],     a0, a1, a2);
    eval_chunks(xr0[2 * q + 1], b0, b1, b2);
    short8 A0[3] = { mk_frag(a0, a1), mk_frag(a2, b0), mk_frag(b1, b2) };
    eval_chunks(xr1[2 * q],     a0, a1, a2);
    eval_chunks(xr1[2 * q + 1], b0, b1, b2);
    short8 A1[3] = { mk_frag(a0, a1), mk_frag(a2, b0), mk_frag(b1, b2) };

    #pragma unroll
    for (int sub = 0; sub < 3; ++sub)
      #pragma unroll
      for (int nt = 0; nt < 2; ++nt) {
        short8 B = __builtin_bit_cast(short8, b01[nt][sub]);
        acc[0][nt] = __builtin_amdgcn_mfma_f32_16x16x32_bf16(A0[sub], B, acc[0][nt], 0, 0, 0);
        acc[1][nt] = __builtin_amdgcn_mfma_f32_16x16x32_bf16(A1[sub], B, acc[1][nt], 0, 0, 0);
      }

    // ---- B-frags nt 2,3 ----
    u32x4 b23[2][3];
    #pragma unroll
    for (int nt = 0; nt < 2; ++nt)
      #pragma unroll
      for (int sub = 0; sub < 3; ++sub)
        b23[nt][sub] = wf4[((nt + 2) * 24 + sbase + sub) * 64 + lane];

    #pragma unroll
    for (int sub = 0; sub < 3; ++sub)
      #pragma unroll
      for (int nt = 0; nt < 2; ++nt) {
        short8 B = __builtin_bit_cast(short8, b23[nt][sub]);
        acc[0][nt + 2] = __builtin_amdgcn_mfma_f32_16x16x32_bf16(A0[sub], B, acc[0][nt + 2], 0, 0, 0);
        acc[1][nt + 2] = __builtin_amdgcn_mfma_f32_16x16x32_bf16(A1[sub], B, acc[1][nt + 2], 0, 0, 0);
      }
  }

  // ---- split-K reduction: kh=1 waves write LDS, kh=0 waves add + store ----
  const int rbase = (rt * 64 + lane) * 33;
  if (kh == 1) {
    #pragma unroll
    for (int mt = 0; mt < 2; ++mt)
      #pragma unroll
      for (int nt = 0; nt < 4; ++nt)
        #pragma unroll
        for (int j = 0; j < 4; ++j)
          red[rbase + mt * 16 + nt * 4 + j] = acc[mt][nt][j];
  }
  __syncthreads();
  if (kh == 0) {
    #pragma unroll
    for (int mt = 0; mt < 2; ++mt)
      #pragma unroll
      for (int nt = 0; nt < 4; ++nt)
        #pragma unroll
        for (int j = 0; j < 4; ++j)
          acc[mt][nt][j] += red[rbase + mt * 16 + nt * 4 + j];
    #pragma unroll
    for (int mt = 0; mt < 2; ++mt)
      #pragma unroll
      for (int nt = 0; nt < 4; ++nt)
        #pragma unroll
        for (int j = 0; j < 4; ++j)
          out[(row0 + mt * 16 + g * 4 + j) * 64 + nt * 16 + m] = acc[mt][nt][j];
  }
}

extern "C" void kernel_launch(void* const* d_in, const int* in_sizes, int n_in,
                              void* d_out, int out_size, void* d_ws, size_t ws_size,
                              hipStream_t stream) {
  const float* x  = (const float*)d_in[0];
  const float* cp = (const float*)d_in[1];
  float* out = (float*)d_out;
  unsigned* wfrag = (unsigned*)d_ws;       // 24576 dwords = 96 KB

  hipLaunchKernelGGL(prep_wfrag, dim3(96), dim3(256), 0, stream, cp, wfrag);
  const int rows = in_sizes[0] / 64;       // 65536
  hipLaunchKernelGGL(kan_mfma, dim3(rows / 128), dim3(THREADS), 0, stream,
                     x, wfrag, out);
}